// Round 5
// baseline (453.811 us; speedup 1.0000x reference)
//
#include <hip/hip_runtime.h>
#include <hip/hip_bf16.h>
#include <stdint.h>
#include <stddef.h>

typedef __bf16 bf16_t;
typedef __bf16 bf16x4_t __attribute__((ext_vector_type(4)));
typedef __bf16 bf16x8_t __attribute__((ext_vector_type(8)));
typedef float f32x4 __attribute__((ext_vector_type(4)));

#define D_MODEL 2048
#define NHEADS 16
#define HDIM 128
#define SEQ 2048
#define BATCH 2
#define MTOT (BATCH * SEQ) /* 4096 */
#define SCALE_F 0.08838834764831845f /* 1/sqrt(128) */
#define LOG2E 1.4426950408889634f
#define QSCALE (SCALE_F * LOG2E)
#define KT 32            /* flash K-tile */
#define NEGI -3.0e38f    /* mask value */
#define MINIT -1.0e30f   /* finite m sentinel: keeps exp2(masked - m) == 0 */

#define AS1 __attribute__((address_space(1)))
#define AS3 __attribute__((address_space(3)))

__device__ __forceinline__ void load_lds16(const bf16_t* g, bf16_t* l) {
  __builtin_amdgcn_global_load_lds((AS1 void*)(g), (AS3 void*)(l), 16, 0, 0);
}

// ---------------------------------------------------------------- casts fp32->bf16
__global__ void cast_kernel(const float* __restrict__ src, bf16_t* __restrict__ dst, int n4) {
  int i = blockIdx.x * blockDim.x + threadIdx.x;
  if (i < n4) {
    float4 v = ((const float4*)src)[i];
    bf16x4_t o;
    o.x = (bf16_t)v.x; o.y = (bf16_t)v.y; o.z = (bf16_t)v.z; o.w = (bf16_t)v.w;
    ((bf16x4_t*)dst)[i] = o;
  }
}

__global__ void cast4_kernel(const float* __restrict__ s0, const float* __restrict__ s1,
                             const float* __restrict__ s2, const float* __restrict__ s3,
                             bf16_t* __restrict__ dst, int n4) {
  int i = blockIdx.x * blockDim.x + threadIdx.x;
  int y = blockIdx.y;
  if (i < n4) {
    const float* src = (y == 0) ? s0 : (y == 1) ? s1 : (y == 2) ? s2 : s3;
    float4 v = ((const float4*)src)[i];
    bf16x4_t o;
    o.x = (bf16_t)v.x; o.y = (bf16_t)v.y; o.z = (bf16_t)v.z; o.w = (bf16_t)v.w;
    ((bf16x4_t*)(dst + (size_t)y * D_MODEL * D_MODEL / 4 * 4))[i] = o;
  }
}

// ---------------------------------------------------------------- GEMM  C = A @ B^T (+bias)
// BK=64, XOR chunk-swizzled LDS. mode 0: N=6144 (q|k|v) -> Q (prescaled by QSCALE), K,
// V transposed. mode 1: N=2048 -> fp32 out + bias.  ~845 TF (m97-structure plateau).
__global__ __launch_bounds__(256) void gemm_fused(
    const bf16_t* __restrict__ A, const bf16_t* __restrict__ Bm, int mode,
    const float* __restrict__ bias0, const float* __restrict__ bias1,
    const float* __restrict__ bias2,
    bf16_t* __restrict__ Qo, bf16_t* __restrict__ Ko, bf16_t* __restrict__ Vto,
    float* __restrict__ Out) {
  const int K = 2048;
  __shared__ __align__(16) bf16_t lA[128 * 64];
  __shared__ __align__(16) bf16_t lB[128 * 64];
  const int m0 = blockIdx.x * 128;
  const int n0 = blockIdx.y * 128;
  const int t = threadIdx.x;
  const int w = t >> 6, lane = t & 63;
  const int wm = w & 1, wn = w >> 1;
  const int la = lane & 15, lb = lane >> 4;

  f32x4 acc[4][4];
  f32x4 zero = {0.f, 0.f, 0.f, 0.f};
#pragma unroll
  for (int i = 0; i < 4; i++)
#pragma unroll
    for (int j = 0; j < 4; j++) acc[i][j] = zero;

  const int row0 = t >> 3, cc = t & 7;
  const int ccs = cc ^ (row0 & 7);
  const bf16_t* gA = A + (size_t)(m0 + row0) * K + ccs * 8;
  const bf16_t* gB = Bm + (size_t)(n0 + row0) * K + ccs * 8;
  bf16_t* sA = lA + t * 8;
  bf16_t* sB = lB + t * 8;

  for (int k0 = 0; k0 < K; k0 += 64) {
    __syncthreads();
#pragma unroll
    for (int i = 0; i < 4; i++)
      load_lds16(gA + k0 + (size_t)(32 * i) * K, sA + 2048 * i);
#pragma unroll
    for (int i = 0; i < 4; i++)
      load_lds16(gB + k0 + (size_t)(32 * i) * K, sB + 2048 * i);
    __syncthreads();
#pragma unroll
    for (int ks = 0; ks < 2; ks++) {
      bf16x8_t af[4], bfr[4];
#pragma unroll
      for (int mt = 0; mt < 4; mt++) {
        int row = wm * 64 + mt * 16 + la;
        af[mt] = *(const bf16x8_t*)(lA + row * 64 + (((ks * 4 + lb) ^ (la & 7)) * 8));
      }
#pragma unroll
      for (int nt = 0; nt < 4; nt++) {
        int row = wn * 64 + nt * 16 + la;
        bfr[nt] = *(const bf16x8_t*)(lB + row * 64 + (((ks * 4 + lb) ^ (la & 7)) * 8));
      }
#pragma unroll
      for (int mt = 0; mt < 4; mt++)
#pragma unroll
        for (int nt = 0; nt < 4; nt++)
          acc[mt][nt] = __builtin_amdgcn_mfma_f32_16x16x32_bf16(af[mt], bfr[nt], acc[mt][nt], 0, 0, 0);
    }
  }

  if (mode == 0) {
#pragma unroll
    for (int mt = 0; mt < 4; mt++) {
#pragma unroll
      for (int nt = 0; nt < 4; nt++) {
        int m = m0 + wm * 64 + mt * 16 + lb * 4;
        int n = n0 + wn * 64 + nt * 16 + la;
        int b = m >> 11, s = m & 2047;
        int which = n >> 11, hd = n & 2047;
        int h = hd >> 7, d = hd & 127;
        float bv = (which == 0 ? bias0 : which == 1 ? bias1 : bias2)[hd];
        f32x4 v = acc[mt][nt];
        if (which == 2) {
          bf16_t* dst = Vto + ((size_t)(b * NHEADS + h) * HDIM + d) * SEQ + s;
          bf16x4_t pk;
          pk.x = (bf16_t)(v.x + bv); pk.y = (bf16_t)(v.y + bv);
          pk.z = (bf16_t)(v.z + bv); pk.w = (bf16_t)(v.w + bv);
          *(bf16x4_t*)dst = pk;
        } else {
          float sc = (which == 0) ? QSCALE : 1.0f;
          bf16_t* dst = (which == 0 ? Qo : Ko) + ((size_t)(b * NHEADS + h) * SEQ + s) * HDIM + d;
          dst[0]        = (bf16_t)((v.x + bv) * sc);
          dst[HDIM]     = (bf16_t)((v.y + bv) * sc);
          dst[2 * HDIM] = (bf16_t)((v.z + bv) * sc);
          dst[3 * HDIM] = (bf16_t)((v.w + bv) * sc);
        }
      }
    }
  } else {
#pragma unroll
    for (int mt = 0; mt < 4; mt++) {
#pragma unroll
      for (int nt = 0; nt < 4; nt++) {
        int m = m0 + wm * 64 + mt * 16 + lb * 4;
        int n = n0 + wn * 64 + nt * 16 + la;
        float bv = bias0[n];
        f32x4 v = acc[mt][nt];
        float* dst = Out + (size_t)m * D_MODEL + n;
        dst[0]           = v.x + bv;
        dst[D_MODEL]     = v.y + bv;
        dst[2 * D_MODEL] = v.z + bv;
        dst[3 * D_MODEL] = v.w + bv;
      }
    }
  }
}

// ---------------------------------------------------------------- causal flash attention
// BARRIER-FREE register-streamed: K/V MFMA fragments load directly global->VGPR
// (no K/V LDS, no __syncthreads anywhere). K double-buffered in regs (prefetch +2 tiles),
// V loaded at step top (~600cyc before PV use). LDS only for the wave-private P transpose.
// Uniform grid: 512 blocks x exactly 34 k-steps (same decomposition as R4).
#define FLASH_STEP(KU, ktc)                                                              \
  {                                                                                      \
    const int j0s = (ktc) * KT;                                                          \
    /* V for this step (used ~S+softmax later) */                                        \
    _Pragma("unroll")                                                                    \
    for (int dt = 0; dt < 8; dt++)                                                       \
      vf[dt] = *(const bf16x8_t*)(Vb + (size_t)(dt * 16 + la) * SEQ + j0s + lb * 8);     \
    /* S^T = K Q^T */                                                                    \
    f32x4 st[2][2];                                                                      \
    _Pragma("unroll")                                                                    \
    for (int nt = 0; nt < 2; nt++)                                                       \
      _Pragma("unroll")                                                                  \
      for (int mt = 0; mt < 2; mt++) st[nt][mt] = zero;                                  \
    _Pragma("unroll")                                                                    \
    for (int ks = 0; ks < 4; ks++)                                                       \
      _Pragma("unroll")                                                                  \
      for (int nt = 0; nt < 2; nt++)                                                     \
        _Pragma("unroll")                                                                \
        for (int mt = 0; mt < 2; mt++)                                                   \
          st[nt][mt] = __builtin_amdgcn_mfma_f32_16x16x32_bf16(KU[ks * 2 + nt],          \
                          qf[mt][ks], st[nt][mt], 0, 0, 0);                              \
    /* prefetch K tile ktc+2 into the buffer just freed (WAR: after S reads) */          \
    {                                                                                    \
      int jp = (ktc + 2) * KT; if (jp > SEQ - KT) jp = SEQ - KT;                         \
      _Pragma("unroll")                                                                  \
      for (int ks = 0; ks < 4; ks++)                                                     \
        _Pragma("unroll")                                                                \
        for (int nt = 0; nt < 2; nt++)                                                   \
          KU[ks * 2 + nt] = *(const bf16x8_t*)(Kb + (size_t)(jp + nt * 16 + la) * HDIM   \
                                               + (ks * 4 + lb) * 8);                     \
    }                                                                                    \
    /* causal mask + online softmax (log2 domain, Q prescaled) */                        \
    const bool dmk = (j0s + KT > q0);                                                    \
    _Pragma("unroll")                                                                    \
    for (int mt = 0; mt < 2; mt++) {                                                     \
      int qg = q0 + qloc + mt * 16;                                                      \
      if (dmk) {                                                                         \
        _Pragma("unroll")                                                                \
        for (int nt = 0; nt < 2; nt++)                                                   \
          _Pragma("unroll")                                                              \
          for (int r = 0; r < 4; r++)                                                    \
            if (j0s + nt * 16 + lb * 4 + r > qg) st[nt][mt][r] = NEGI;                   \
      }                                                                                  \
      float tm = NEGI;                                                                   \
      _Pragma("unroll")                                                                  \
      for (int nt = 0; nt < 2; nt++)                                                     \
        _Pragma("unroll")                                                                \
        for (int r = 0; r < 4; r++) tm = fmaxf(tm, st[nt][mt][r]);                       \
      tm = fmaxf(tm, __shfl_xor(tm, 16));                                                \
      tm = fmaxf(tm, __shfl_xor(tm, 32));                                                \
      float mnew = fmaxf(mr[mt], tm);                                                    \
      float alpha = exp2f(mr[mt] - mnew);                                                \
      mr[mt] = mnew;                                                                     \
      lr[mt] *= alpha;                                                                   \
      _Pragma("unroll")                                                                  \
      for (int dt = 0; dt < 8; dt++) oacc[mt][dt] *= alpha;                              \
      float s = 0.f;                                                                     \
      _Pragma("unroll")                                                                  \
      for (int nt = 0; nt < 2; nt++) {                                                   \
        f32x4 pv;                                                                        \
        _Pragma("unroll")                                                                \
        for (int r = 0; r < 4; r++) { pv[r] = exp2f(st[nt][mt][r] - mnew); s += pv[r]; } \
        bf16x4_t pk;                                                                     \
        pk.x = (bf16_t)pv[0]; pk.y = (bf16_t)pv[1];                                      \
        pk.z = (bf16_t)pv[2]; pk.w = (bf16_t)pv[3];                                      \
        *(bf16x4_t*)(lP + (qloc + mt * 16) * 40 + nt * 16 + lb * 4) = pk;                \
      }                                                                                  \
      s += __shfl_xor(s, 16);                                                            \
      s += __shfl_xor(s, 32);                                                            \
      lr[mt] += s;                                                                       \
    }                                                                                    \
    /* O^T += V^T P^T (wave-private lP rows -> lgkm ordering suffices, no barrier) */    \
    bf16x8_t pf[2];                                                                      \
    _Pragma("unroll")                                                                    \
    for (int mt = 0; mt < 2; mt++)                                                       \
      pf[mt] = *(const bf16x8_t*)(lP + (qloc + mt * 16) * 40 + lb * 8);                  \
    _Pragma("unroll")                                                                    \
    for (int dt = 0; dt < 8; dt++)                                                       \
      _Pragma("unroll")                                                                  \
      for (int mt = 0; mt < 2; mt++)                                                     \
        oacc[mt][dt] = __builtin_amdgcn_mfma_f32_16x16x32_bf16(vf[dt], pf[mt],           \
                          oacc[mt][dt], 0, 0, 0);                                        \
  }

__global__ __launch_bounds__(256, 2) void flash_attn(
    const bf16_t* __restrict__ Q, const bf16_t* __restrict__ Kg,
    const bf16_t* __restrict__ Vt, bf16_t* __restrict__ O,
    bf16_t* __restrict__ PO, float* __restrict__ ML) {
  __shared__ __align__(16) bf16_t lP[128 * 40];  // P^T as [q][j], stride 40; 10KB
  const int g = blockIdx.x;
  const int bh = g & 31, idx = g >> 5;
  const int t = threadIdx.x;
  const int w = t >> 6, lane = t & 63;
  const int la = lane & 15, lb = lane >> 4;
  const int qloc = w * 32 + la;

  const bf16_t* Qb = Q + (size_t)bh * SEQ * HDIM;
  const bf16_t* Kb = Kg + (size_t)bh * SEQ * HDIM;
  const bf16_t* Vb = Vt + (size_t)bh * HDIM * SEQ;
  const int b = bh >> 4, h = bh & 15;

  int nph, qts[2], k0s[2], k1s[2], slots[2];
  bool parts[2];
  if (idx < 8) {
    nph = 1; qts[0] = 8 + idx; k0s[0] = 0; k1s[0] = 34;
    parts[0] = true; slots[0] = (idx * 32 + bh) * 2;
  } else {
    int qtA = idx - 8;
    nph = 2;
    qts[0] = qtA; k0s[0] = 0; k1s[0] = 4 * qtA + 4; parts[0] = false; slots[0] = 0;
    qts[1] = 15 - qtA; k0s[1] = 34; k1s[1] = 64 - 4 * qtA;
    parts[1] = true; slots[1] = ((7 - qtA) * 32 + bh) * 2 + 1;
  }

  for (int ph = 0; ph < nph; ph++) {
    const int qt = qts[ph], kt0 = k0s[ph], kt1 = k1s[ph];
    const int q0 = qt * 128;

    // Q fragments (B-operand), prescaled by QSCALE in the QKV epilogue
    bf16x8_t qf[2][4];
#pragma unroll
    for (int mt = 0; mt < 2; mt++)
#pragma unroll
      for (int ks = 0; ks < 4; ks++)
        qf[mt][ks] = *(const bf16x8_t*)(Qb + (size_t)(q0 + qloc + mt * 16) * HDIM + ks * 32 + lb * 8);

    f32x4 oacc[2][8];
    float mr[2] = {MINIT, MINIT}, lr[2] = {0.f, 0.f};
    f32x4 zero = {0.f, 0.f, 0.f, 0.f};
#pragma unroll
    for (int mt = 0; mt < 2; mt++)
#pragma unroll
      for (int dt = 0; dt < 8; dt++) oacc[mt][dt] = zero;

    bf16x8_t kfA[8], kfB[8], vf[8];
    // prologue: K tiles kt0 (A) and kt0+1 (B); kt1-kt0 >= 2 always in this decomposition
    {
      const int jA = kt0 * KT;
      int jB = (kt0 + 1) * KT; if (jB > SEQ - KT) jB = SEQ - KT;
#pragma unroll
      for (int ks = 0; ks < 4; ks++)
#pragma unroll
        for (int nt = 0; nt < 2; nt++) {
          kfA[ks * 2 + nt] = *(const bf16x8_t*)(Kb + (size_t)(jA + nt * 16 + la) * HDIM + (ks * 4 + lb) * 8);
          kfB[ks * 2 + nt] = *(const bf16x8_t*)(Kb + (size_t)(jB + nt * 16 + la) * HDIM + (ks * 4 + lb) * 8);
        }
    }

    for (int kt = kt0; kt < kt1; kt += 2) {
      FLASH_STEP(kfA, kt);
      if (kt + 1 < kt1) FLASH_STEP(kfB, kt + 1);
    }

    if (!parts[ph]) {
#pragma unroll
      for (int mt = 0; mt < 2; mt++) {
        float inv = 1.0f / lr[mt];
        int q = q0 + qloc + mt * 16;
        bf16_t* dst = O + ((size_t)b * SEQ + q) * D_MODEL + h * HDIM + lb * 4;
#pragma unroll
        for (int dt = 0; dt < 8; dt++) {
          f32x4 v = oacc[mt][dt];
          bf16x4_t pk;
          pk.x = (bf16_t)(v[0] * inv); pk.y = (bf16_t)(v[1] * inv);
          pk.z = (bf16_t)(v[2] * inv); pk.w = (bf16_t)(v[3] * inv);
          *(bf16x4_t*)(dst + dt * 16) = pk;
        }
      }
    } else {
      const int slot = slots[ph];
      bf16_t* pob = PO + (size_t)slot * 128 * 128;
#pragma unroll
      for (int mt = 0; mt < 2; mt++) {
        int q = qloc + mt * 16;
        bf16_t* dst = pob + (size_t)q * 128 + lb * 4;
#pragma unroll
        for (int dt = 0; dt < 8; dt++) {
          f32x4 v = oacc[mt][dt];
          bf16x4_t pk;
          pk.x = (bf16_t)v[0]; pk.y = (bf16_t)v[1];
          pk.z = (bf16_t)v[2]; pk.w = (bf16_t)v[3];
          *(bf16x4_t*)(dst + dt * 16) = pk;
        }
        if (lb == 0) {
          float2 ml = make_float2(mr[mt], lr[mt]);
          *(float2*)(ML + ((size_t)slot * 128 + q) * 2) = ml;
        }
      }
    }
  }
}

// ---------------------------------------------------------------- merge split-j partials
__global__ void merge_kernel(const bf16_t* __restrict__ PO, const float* __restrict__ ML,
                             bf16_t* __restrict__ O) {
  const int qti = blockIdx.x >> 5, bh = blockIdx.x & 31;
  const int qt = 8 + qti;
  const int t = threadIdx.x;
  const int q = t >> 1, dh = (t & 1) * 64;
  const size_t s1 = ((size_t)(qti * 32 + bh)) * 2;
  const float* ml1 = ML + (s1 * 128 + q) * 2;
  const float* ml2 = ML + ((s1 + 1) * 128 + q) * 2;
  float m1 = ml1[0], l1 = ml1[1], m2 = ml2[0], l2 = ml2[1];
  float m = fmaxf(m1, m2);
  float w1 = exp2f(m1 - m), w2 = exp2f(m2 - m);
  float inv = 1.0f / (w1 * l1 + w2 * l2);
  w1 *= inv; w2 *= inv;
  const bf16_t* p1 = PO + (s1 * 128 + q) * 128 + dh;
  const bf16_t* p2 = PO + ((s1 + 1) * 128 + q) * 128 + dh;
  const int b = bh >> 4, h = bh & 15;
  bf16_t* dst = O + ((size_t)b * SEQ + qt * 128 + q) * D_MODEL + h * HDIM + dh;
#pragma unroll
  for (int i = 0; i < 8; i++) {
    bf16x8_t a = ((const bf16x8_t*)p1)[i];
    bf16x8_t c = ((const bf16x8_t*)p2)[i];
    bf16x8_t o;
#pragma unroll
    for (int e = 0; e < 8; e++)
      o[e] = (bf16_t)(w1 * (float)a[e] + w2 * (float)c[e]);
    ((bf16x8_t*)dst)[i] = o;
  }
}

// ---------------------------------------------------------------- launch
extern "C" void kernel_launch(void* const* d_in, const int* in_sizes, int n_in,
                              void* d_out, int out_size, void* d_ws, size_t ws_size,
                              hipStream_t stream) {
  (void)in_sizes; (void)n_in; (void)out_size; (void)ws_size;
  const float* x  = (const float*)d_in[0];
  const float* Wq = (const float*)d_in[2];
  const float* bq = (const float*)d_in[3];
  const float* Wk = (const float*)d_in[4];
  const float* bk = (const float*)d_in[5];
  const float* Wv = (const float*)d_in[6];
  const float* bv = (const float*)d_in[7];
  const float* Wo = (const float*)d_in[8];
  const float* bo = (const float*)d_in[9];
  float* out = (float*)d_out;

  const size_t NBF = (size_t)MTOT * D_MODEL * sizeof(bf16_t);    // 16.8 MB
  const size_t WBF = (size_t)D_MODEL * D_MODEL * sizeof(bf16_t); // 8.4 MB
  char* p = (char*)d_ws;
  bf16_t* xb   = (bf16_t*)p; p += NBF;       // reused as attention output O
  bf16_t* Wcat = (bf16_t*)p; p += 4 * WBF;   // [Wq|Wk|Wv|Wo] bf16
  bf16_t* Qb   = (bf16_t*)p; p += NBF;
  bf16_t* Kb   = (bf16_t*)p; p += NBF;
  bf16_t* Vtb  = (bf16_t*)p; p += NBF;
  bf16_t* Wob  = Wcat + (size_t)3 * D_MODEL * D_MODEL;
  bf16_t* Ob   = xb;
  // Partial buffers overlay dead Wq|Wk|Wv bf16 slots (dead after QKV GEMM):
  bf16_t* PO = Wcat;                                     // 512 slots * 16384 bf16 = 16.8 MB
  float*  ML = (float*)(Wcat + (size_t)512 * 128 * 128); // 0.5 MB

  const int WN4 = D_MODEL * D_MODEL / 4;
  const int XN4 = MTOT * D_MODEL / 4;
  cast_kernel<<<XN4 / 256, 256, 0, stream>>>(x, xb, XN4);
  cast4_kernel<<<dim3(WN4 / 256, 4), 256, 0, stream>>>(Wq, Wk, Wv, Wo, Wcat, WN4);

  gemm_fused<<<dim3(MTOT / 128, 6144 / 128), 256, 0, stream>>>(
      xb, Wcat, 0, bq, bk, bv, Qb, Kb, Vtb, nullptr);

  flash_attn<<<dim3(512), 256, 0, stream>>>(Qb, Kb, Vtb, Ob, PO, ML);
  merge_kernel<<<dim3(256), 256, 0, stream>>>(PO, ML, Ob);

  gemm_fused<<<dim3(MTOT / 128, D_MODEL / 128), 256, 0, stream>>>(
      Ob, Wob, 1, bo, nullptr, nullptr, nullptr, nullptr, nullptr, out);
}

// Round 6
// 407.754 us; speedup vs baseline: 1.1130x; 1.1130x over previous
//
#include <hip/hip_runtime.h>
#include <hip/hip_bf16.h>
#include <stdint.h>
#include <stddef.h>

typedef __bf16 bf16_t;
typedef __bf16 bf16x4_t __attribute__((ext_vector_type(4)));
typedef __bf16 bf16x8_t __attribute__((ext_vector_type(8)));
typedef float f32x4 __attribute__((ext_vector_type(4)));

#define D_MODEL 2048
#define NHEADS 16
#define HDIM 128
#define SEQ 2048
#define BATCH 2
#define MTOT (BATCH * SEQ) /* 4096 */
#define SCALE_F 0.08838834764831845f /* 1/sqrt(128) */
#define LOG2E 1.4426950408889634f
#define QSCALE (SCALE_F * LOG2E)
#define KT 32            /* flash K-tile */
#define NEGI -3.0e38f    /* mask value */
#define MINIT -1.0e30f   /* finite m sentinel: keeps exp2(masked - m) == 0 */

#define AS1 __attribute__((address_space(1)))
#define AS3 __attribute__((address_space(3)))

__device__ __forceinline__ void load_lds16(const bf16_t* g, bf16_t* l) {
  __builtin_amdgcn_global_load_lds((AS1 void*)(g), (AS3 void*)(l), 16, 0, 0);
}

// ---------------------------------------------------------------- casts fp32->bf16
__global__ void cast_kernel(const float* __restrict__ src, bf16_t* __restrict__ dst, int n4) {
  int i = blockIdx.x * blockDim.x + threadIdx.x;
  if (i < n4) {
    float4 v = ((const float4*)src)[i];
    bf16x4_t o;
    o.x = (bf16_t)v.x; o.y = (bf16_t)v.y; o.z = (bf16_t)v.z; o.w = (bf16_t)v.w;
    ((bf16x4_t*)dst)[i] = o;
  }
}

__global__ void cast4_kernel(const float* __restrict__ s0, const float* __restrict__ s1,
                             const float* __restrict__ s2, const float* __restrict__ s3,
                             bf16_t* __restrict__ dst, int n4) {
  int i = blockIdx.x * blockDim.x + threadIdx.x;
  int y = blockIdx.y;
  if (i < n4) {
    const float* src = (y == 0) ? s0 : (y == 1) ? s1 : (y == 2) ? s2 : s3;
    float4 v = ((const float4*)src)[i];
    bf16x4_t o;
    o.x = (bf16_t)v.x; o.y = (bf16_t)v.y; o.z = (bf16_t)v.z; o.w = (bf16_t)v.w;
    ((bf16x4_t*)(dst + (size_t)y * D_MODEL * D_MODEL / 4 * 4))[i] = o;
  }
}

// ---------------------------------------------------------------- GEMM  C = A @ B^T (+bias)
// BK=64, XOR chunk-swizzled LDS. mode 0: N=6144 (q|k|v) -> Q (prescaled by QSCALE), K,
// V transposed. mode 1: N=2048 -> fp32 out + bias.  ~845 TF (m97-structure plateau).
__global__ __launch_bounds__(256) void gemm_fused(
    const bf16_t* __restrict__ A, const bf16_t* __restrict__ Bm, int mode,
    const float* __restrict__ bias0, const float* __restrict__ bias1,
    const float* __restrict__ bias2,
    bf16_t* __restrict__ Qo, bf16_t* __restrict__ Ko, bf16_t* __restrict__ Vto,
    float* __restrict__ Out) {
  const int K = 2048;
  __shared__ __align__(16) bf16_t lA[128 * 64];
  __shared__ __align__(16) bf16_t lB[128 * 64];
  const int m0 = blockIdx.x * 128;
  const int n0 = blockIdx.y * 128;
  const int t = threadIdx.x;
  const int w = t >> 6, lane = t & 63;
  const int wm = w & 1, wn = w >> 1;
  const int la = lane & 15, lb = lane >> 4;

  f32x4 acc[4][4];
  f32x4 zero = {0.f, 0.f, 0.f, 0.f};
#pragma unroll
  for (int i = 0; i < 4; i++)
#pragma unroll
    for (int j = 0; j < 4; j++) acc[i][j] = zero;

  const int row0 = t >> 3, cc = t & 7;
  const int ccs = cc ^ (row0 & 7);
  const bf16_t* gA = A + (size_t)(m0 + row0) * K + ccs * 8;
  const bf16_t* gB = Bm + (size_t)(n0 + row0) * K + ccs * 8;
  bf16_t* sA = lA + t * 8;
  bf16_t* sB = lB + t * 8;

  for (int k0 = 0; k0 < K; k0 += 64) {
    __syncthreads();
#pragma unroll
    for (int i = 0; i < 4; i++)
      load_lds16(gA + k0 + (size_t)(32 * i) * K, sA + 2048 * i);
#pragma unroll
    for (int i = 0; i < 4; i++)
      load_lds16(gB + k0 + (size_t)(32 * i) * K, sB + 2048 * i);
    __syncthreads();
#pragma unroll
    for (int ks = 0; ks < 2; ks++) {
      bf16x8_t af[4], bfr[4];
#pragma unroll
      for (int mt = 0; mt < 4; mt++) {
        int row = wm * 64 + mt * 16 + la;
        af[mt] = *(const bf16x8_t*)(lA + row * 64 + (((ks * 4 + lb) ^ (la & 7)) * 8));
      }
#pragma unroll
      for (int nt = 0; nt < 4; nt++) {
        int row = wn * 64 + nt * 16 + la;
        bfr[nt] = *(const bf16x8_t*)(lB + row * 64 + (((ks * 4 + lb) ^ (la & 7)) * 8));
      }
#pragma unroll
      for (int mt = 0; mt < 4; mt++)
#pragma unroll
        for (int nt = 0; nt < 4; nt++)
          acc[mt][nt] = __builtin_amdgcn_mfma_f32_16x16x32_bf16(af[mt], bfr[nt], acc[mt][nt], 0, 0, 0);
    }
  }

  if (mode == 0) {
#pragma unroll
    for (int mt = 0; mt < 4; mt++) {
#pragma unroll
      for (int nt = 0; nt < 4; nt++) {
        int m = m0 + wm * 64 + mt * 16 + lb * 4;
        int n = n0 + wn * 64 + nt * 16 + la;
        int b = m >> 11, s = m & 2047;
        int which = n >> 11, hd = n & 2047;
        int h = hd >> 7, d = hd & 127;
        float bv = (which == 0 ? bias0 : which == 1 ? bias1 : bias2)[hd];
        f32x4 v = acc[mt][nt];
        if (which == 2) {
          bf16_t* dst = Vto + ((size_t)(b * NHEADS + h) * HDIM + d) * SEQ + s;
          bf16x4_t pk;
          pk.x = (bf16_t)(v.x + bv); pk.y = (bf16_t)(v.y + bv);
          pk.z = (bf16_t)(v.z + bv); pk.w = (bf16_t)(v.w + bv);
          *(bf16x4_t*)dst = pk;
        } else {
          float sc = (which == 0) ? QSCALE : 1.0f;
          bf16_t* dst = (which == 0 ? Qo : Ko) + ((size_t)(b * NHEADS + h) * SEQ + s) * HDIM + d;
          dst[0]        = (bf16_t)((v.x + bv) * sc);
          dst[HDIM]     = (bf16_t)((v.y + bv) * sc);
          dst[2 * HDIM] = (bf16_t)((v.z + bv) * sc);
          dst[3 * HDIM] = (bf16_t)((v.w + bv) * sc);
        }
      }
    }
  } else {
#pragma unroll
    for (int mt = 0; mt < 4; mt++) {
#pragma unroll
      for (int nt = 0; nt < 4; nt++) {
        int m = m0 + wm * 64 + mt * 16 + lb * 4;
        int n = n0 + wn * 64 + nt * 16 + la;
        float bv = bias0[n];
        f32x4 v = acc[mt][nt];
        float* dst = Out + (size_t)m * D_MODEL + n;
        dst[0]           = v.x + bv;
        dst[D_MODEL]     = v.y + bv;
        dst[2 * D_MODEL] = v.z + bv;
        dst[3 * D_MODEL] = v.w + bv;
      }
    }
  }
}

// ---------------------------------------------------------------- causal flash attention
// R4 dbuf-LDS body (known good) + 768-block uniform decomposition for 3 blocks/CU.
// Pair p = (qtA=p, qtB=15-p) has 68 k-steps; piece i in {0,1,2} takes steps
// [{0,23,46}[i], {23,46,68}[i]) of the concatenated (qtA then qtB) sequence.
// qtA (<=20 steps for p<=4) is full inside piece0 -> direct write; all other
// segments write (PO, ML) partials merged by merge_kernel.
// Slot map per bh (27 slots): pair<5 -> base 3*pair, qtB segs local={piece};
// pair>=5 -> base 15+4*(pair-5), qtA segs local={0,1}, qtB segs local={2,3}.
__global__ __launch_bounds__(256, 3) void flash_attn(
    const bf16_t* __restrict__ Q, const bf16_t* __restrict__ Kg,
    const bf16_t* __restrict__ Vt, bf16_t* __restrict__ O,
    bf16_t* __restrict__ PO, float* __restrict__ ML) {
  __shared__ __align__(16) bf16_t lK[2][KT * 128];   // [j][d] chunks, swizzled; 2x8KB
  __shared__ __align__(16) bf16_t lV[2][128 * KT];   // [d][j] chunks, swizzled; 2x8KB
  __shared__ __align__(16) bf16_t lP[128 * 40];      // P^T as [q][j], stride 40; 10KB
  const int g = blockIdx.x;
  const int bh = g & 31, pc = g >> 5;        // pc in 0..23
  const int pair = pc / 3, piece = pc % 3;
  const int nA = 4 * pair + 4;
  const int lo = (piece == 0) ? 0 : ((piece == 1) ? 23 : 46);
  const int hi = (piece == 2) ? 68 : (lo + 23);
  const int baseP = (pair < 5) ? (3 * pair) : (15 + 4 * (pair - 5));

  const int t = threadIdx.x;
  const int w = t >> 6, lane = t & 63;
  const int la = lane & 15, lb = lane >> 4;
  const int qloc = w * 32 + la;

  const bf16_t* Qb = Q + (size_t)bh * SEQ * HDIM;
  const bf16_t* Kb = Kg + (size_t)bh * SEQ * HDIM;
  const bf16_t* Vb = Vt + (size_t)bh * HDIM * SEQ;
  const int b = bh >> 4, h = bh & 15;

  int nph = 0, qts[2], k0s[2], k1s[2], slots[2];
  bool parts[2];
  {  // phase on qtA
    int k0 = lo, k1 = (hi < nA) ? hi : nA;
    if (k1 > k0) {
      qts[nph] = pair; k0s[nph] = k0; k1s[nph] = k1;
      parts[nph] = !(k0 == 0 && k1 == nA);
      slots[nph] = bh * 27 + baseP + piece;   // piece in {0,1} when partial
      nph++;
    }
  }
  {  // phase on qtB
    int k0 = ((lo > nA) ? lo : nA) - nA, k1 = hi - nA;
    if (k1 > k0) {
      qts[nph] = 15 - pair; k0s[nph] = k0; k1s[nph] = k1;
      parts[nph] = true;  // qtB (>=36 steps) never fits one piece
      int localB = (pair < 5) ? piece : (piece + 1);  // pair>=5: pieces 1,2 -> 2,3
      slots[nph] = bh * 27 + baseP + localB;
      nph++;
    }
  }

  // staging lane roles (fixed per thread)
  const int kj = t >> 4, kcc = t & 15;  // K: 2 iters cover 32 rows x 16 chunks
  const int vd = t >> 2, vjc = t & 3;   // V: 2 iters cover 128 rows x 4 chunks

  for (int ph = 0; ph < nph; ph++) {
    const int qt = qts[ph], kt0 = k0s[ph], kt1 = k1s[ph];
    const int q0 = qt * 128;

    // Q fragments (B-operand), prescaled by QSCALE in the QKV epilogue
    bf16x8_t qf[2][4];
#pragma unroll
    for (int mt = 0; mt < 2; mt++)
#pragma unroll
      for (int ks = 0; ks < 4; ks++)
        qf[mt][ks] = *(const bf16x8_t*)(Qb + (size_t)(q0 + qloc + mt * 16) * HDIM + ks * 32 + lb * 8);

    f32x4 oacc[2][8];
    float mr[2] = {MINIT, MINIT}, lr[2] = {0.f, 0.f};
    f32x4 zero = {0.f, 0.f, 0.f, 0.f};
#pragma unroll
    for (int mt = 0; mt < 2; mt++)
#pragma unroll
      for (int dt = 0; dt < 8; dt++) oacc[mt][dt] = zero;

    // prefetch first tile (barrier protects buffers still read by previous phase)
    __syncthreads();
    {
      const int j0 = kt0 * KT;
      int buf = kt0 & 1;
#pragma unroll
      for (int i = 0; i < 2; i++) {
        int j = kj + 16 * i;
        load_lds16(Kb + (size_t)(j0 + j) * HDIM + (((kcc ^ (j & 15))) * 8),
                   lK[buf] + (t + 256 * i) * 8);
      }
#pragma unroll
      for (int i = 0; i < 2; i++) {
        int d = vd + 64 * i;
        load_lds16(Vb + (size_t)d * SEQ + j0 + (((vjc ^ ((d & 3) ^ ((d >> 2) & 3)))) * 8),
                   lV[buf] + (t + 256 * i) * 8);
      }
    }

    for (int kt = kt0; kt < kt1; kt++) {
      const int j0 = kt * KT;
      const int cur = kt & 1;
      __syncthreads();  // waits stage(kt); cheap when prefetched a full compute-phase ago

      if (kt + 1 < kt1) {  // prefetch tile kt+1 into the other buffer
        const int jn = (kt + 1) * KT;
        const int nb = cur ^ 1;
#pragma unroll
        for (int i = 0; i < 2; i++) {
          int j = kj + 16 * i;
          load_lds16(Kb + (size_t)(jn + j) * HDIM + (((kcc ^ (j & 15))) * 8),
                     lK[nb] + (t + 256 * i) * 8);
        }
#pragma unroll
        for (int i = 0; i < 2; i++) {
          int d = vd + 64 * i;
          load_lds16(Vb + (size_t)d * SEQ + jn + (((vjc ^ ((d & 3) ^ ((d >> 2) & 3)))) * 8),
                     lV[nb] + (t + 256 * i) * 8);
        }
      }

      // S^T = K Q^T : rows j (2 nt tiles of 16), cols q (2 mt tiles)
      f32x4 st[2][2];
#pragma unroll
      for (int nt = 0; nt < 2; nt++)
#pragma unroll
        for (int mt = 0; mt < 2; mt++) st[nt][mt] = zero;
#pragma unroll
      for (int ks = 0; ks < 4; ks++) {
#pragma unroll
        for (int nt = 0; nt < 2; nt++) {
          int j = nt * 16 + la;
          int ck = (ks * 4 + lb) ^ (j & 15);
          bf16x8_t kf = *(const bf16x8_t*)(lK[cur] + j * 128 + ck * 8);
#pragma unroll
          for (int mt = 0; mt < 2; mt++)
            st[nt][mt] = __builtin_amdgcn_mfma_f32_16x16x32_bf16(kf, qf[mt][ks], st[nt][mt], 0, 0, 0);
        }
      }

      const bool dm = (j0 + KT > q0);  // diagonal-straddling (block-uniform)
#pragma unroll
      for (int mt = 0; mt < 2; mt++) {
        int qg = q0 + qloc + mt * 16;
        if (dm) {
#pragma unroll
          for (int nt = 0; nt < 2; nt++)
#pragma unroll
            for (int r = 0; r < 4; r++)
              if (j0 + nt * 16 + lb * 4 + r > qg) st[nt][mt][r] = NEGI;
        }
        float tm = NEGI;
#pragma unroll
        for (int nt = 0; nt < 2; nt++)
#pragma unroll
          for (int r = 0; r < 4; r++) tm = fmaxf(tm, st[nt][mt][r]);
        tm = fmaxf(tm, __shfl_xor(tm, 16));
        tm = fmaxf(tm, __shfl_xor(tm, 32));
        float mnew = fmaxf(mr[mt], tm);
        float alpha = exp2f(mr[mt] - mnew);
        mr[mt] = mnew;
        lr[mt] *= alpha;
#pragma unroll
        for (int dt = 0; dt < 8; dt++) oacc[mt][dt] *= alpha;
        float s = 0.f;
#pragma unroll
        for (int nt = 0; nt < 2; nt++) {
          f32x4 p;
#pragma unroll
          for (int r = 0; r < 4; r++) {
            p[r] = exp2f(st[nt][mt][r] - mnew);
            s += p[r];
          }
          bf16x4_t pk;
          pk.x = (bf16_t)p[0]; pk.y = (bf16_t)p[1]; pk.z = (bf16_t)p[2]; pk.w = (bf16_t)p[3];
          *(bf16x4_t*)(lP + (qloc + mt * 16) * 40 + nt * 16 + lb * 4) = pk;
        }
        s += __shfl_xor(s, 16);
        s += __shfl_xor(s, 32);
        lr[mt] += s;
      }

      // O^T += V^T P^T  (K-dim = 32 -> single ks)
      bf16x8_t pf[2];
#pragma unroll
      for (int mt = 0; mt < 2; mt++)
        pf[mt] = *(const bf16x8_t*)(lP + (qloc + mt * 16) * 40 + lb * 8);
#pragma unroll
      for (int dt = 0; dt < 8; dt++) {
        int d = dt * 16 + la;
        int jc = lb ^ ((d & 3) ^ ((d >> 2) & 3));
        bf16x8_t vf = *(const bf16x8_t*)(lV[cur] + d * 32 + jc * 8);
#pragma unroll
        for (int mt = 0; mt < 2; mt++)
          oacc[mt][dt] = __builtin_amdgcn_mfma_f32_16x16x32_bf16(vf, pf[mt], oacc[mt][dt], 0, 0, 0);
      }
    }

    if (!parts[ph]) {
#pragma unroll
      for (int mt = 0; mt < 2; mt++) {
        float inv = 1.0f / lr[mt];
        int q = q0 + qloc + mt * 16;
        bf16_t* dst = O + ((size_t)b * SEQ + q) * D_MODEL + h * HDIM + lb * 4;
#pragma unroll
        for (int dt = 0; dt < 8; dt++) {
          f32x4 v = oacc[mt][dt];
          bf16x4_t pk;
          pk.x = (bf16_t)(v[0] * inv); pk.y = (bf16_t)(v[1] * inv);
          pk.z = (bf16_t)(v[2] * inv); pk.w = (bf16_t)(v[3] * inv);
          *(bf16x4_t*)(dst + dt * 16) = pk;
        }
      }
    } else {
      const int slot = slots[ph];
      bf16_t* pob = PO + (size_t)slot * 128 * 128;
#pragma unroll
      for (int mt = 0; mt < 2; mt++) {
        int q = qloc + mt * 16;
        bf16_t* dst = pob + (size_t)q * 128 + lb * 4;
#pragma unroll
        for (int dt = 0; dt < 8; dt++) {
          f32x4 v = oacc[mt][dt];
          bf16x4_t pk;
          pk.x = (bf16_t)v[0]; pk.y = (bf16_t)v[1];
          pk.z = (bf16_t)v[2]; pk.w = (bf16_t)v[3];
          *(bf16x4_t*)(dst + dt * 16) = pk;
        }
        if (lb == 0) {
          float2 ml = make_float2(mr[mt], lr[mt]);
          *(float2*)(ML + ((size_t)slot * 128 + q) * 2) = ml;
        }
      }
    }
  }
}

// ---------------------------------------------------------------- merge split-j partials
// Grid 352 = 32 bh x 11 merge-tiles. mi<5: pair=mi, qt=15-mi, 3 segs at base+{0,1,2}.
// mi>=5: j=mi-5; pair=5+j/2; j odd -> qtB (segs base+{2,3}), even -> qtA (base+{0,1}).
__global__ void merge_kernel(const bf16_t* __restrict__ PO, const float* __restrict__ ML,
                             bf16_t* __restrict__ O) {
  const int bhi = blockIdx.x;
  const int bh = bhi / 11, mi = bhi % 11;
  int qt, nseg, s0;
  if (mi < 5) {
    qt = 15 - mi; nseg = 3; s0 = 3 * mi;
  } else {
    int j = mi - 5;
    int pair = 5 + (j >> 1);
    bool isB = (j & 1) != 0;
    qt = isB ? (15 - pair) : pair;
    nseg = 2;
    s0 = 15 + 4 * (pair - 5) + (isB ? 2 : 0);
  }
  s0 += bh * 27;
  const int t = threadIdx.x;
  const int q = t >> 1, dh = (t & 1) * 64;

  float m0 = ML[((size_t)s0 * 128 + q) * 2],       l0 = ML[((size_t)s0 * 128 + q) * 2 + 1];
  float m1 = ML[((size_t)(s0 + 1) * 128 + q) * 2], l1 = ML[((size_t)(s0 + 1) * 128 + q) * 2 + 1];
  float m2 = MINIT, l2 = 0.f;
  if (nseg == 3) {
    m2 = ML[((size_t)(s0 + 2) * 128 + q) * 2];
    l2 = ML[((size_t)(s0 + 2) * 128 + q) * 2 + 1];
  }
  float m = fmaxf(fmaxf(m0, m1), m2);
  float w0 = exp2f(m0 - m), w1 = exp2f(m1 - m), w2 = (nseg == 3) ? exp2f(m2 - m) : 0.f;
  float inv = 1.0f / (w0 * l0 + w1 * l1 + w2 * l2);
  w0 *= inv; w1 *= inv; w2 *= inv;

  const bf16_t* p0 = PO + ((size_t)s0 * 128 + q) * 128 + dh;
  const bf16_t* p1 = PO + ((size_t)(s0 + 1) * 128 + q) * 128 + dh;
  const bf16_t* p2 = PO + ((size_t)(s0 + 2) * 128 + q) * 128 + dh;
  const int b = bh >> 4, h = bh & 15;
  bf16_t* dst = O + ((size_t)b * SEQ + qt * 128 + q) * D_MODEL + h * HDIM + dh;
#pragma unroll
  for (int i = 0; i < 8; i++) {
    bf16x8_t a = ((const bf16x8_t*)p0)[i];
    bf16x8_t c = ((const bf16x8_t*)p1)[i];
    bf16x8_t o;
    if (nseg == 3) {
      bf16x8_t e = ((const bf16x8_t*)p2)[i];
#pragma unroll
      for (int k = 0; k < 8; k++)
        o[k] = (bf16_t)(w0 * (float)a[k] + w1 * (float)c[k] + w2 * (float)e[k]);
    } else {
#pragma unroll
      for (int k = 0; k < 8; k++)
        o[k] = (bf16_t)(w0 * (float)a[k] + w1 * (float)c[k]);
    }
    ((bf16x8_t*)dst)[i] = o;
  }
}

// ---------------------------------------------------------------- launch
extern "C" void kernel_launch(void* const* d_in, const int* in_sizes, int n_in,
                              void* d_out, int out_size, void* d_ws, size_t ws_size,
                              hipStream_t stream) {
  (void)in_sizes; (void)n_in; (void)out_size; (void)ws_size;
  const float* x  = (const float*)d_in[0];
  const float* Wq = (const float*)d_in[2];
  const float* bq = (const float*)d_in[3];
  const float* Wk = (const float*)d_in[4];
  const float* bk = (const float*)d_in[5];
  const float* Wv = (const float*)d_in[6];
  const float* bv = (const float*)d_in[7];
  const float* Wo = (const float*)d_in[8];
  const float* bo = (const float*)d_in[9];
  float* out = (float*)d_out;

  const size_t NBF = (size_t)MTOT * D_MODEL * sizeof(bf16_t);    // 16.8 MB
  const size_t WBF = (size_t)D_MODEL * D_MODEL * sizeof(bf16_t); // 8.4 MB
  char* p = (char*)d_ws;
  bf16_t* xb   = (bf16_t*)p; p += NBF;       // reused as attention output O
  bf16_t* Wcat = (bf16_t*)p; p += 4 * WBF;   // [Wq|Wk|Wv|Wo] bf16
  bf16_t* Qb   = (bf16_t*)p; p += NBF;
  bf16_t* Kb   = (bf16_t*)p; p += NBF;
  bf16_t* Vtb  = (bf16_t*)p; p += NBF;
  bf16_t* Wob  = Wcat + (size_t)3 * D_MODEL * D_MODEL;
  bf16_t* Ob   = xb;
  // Partial O tiles live in d_out (dead until the final GEMM overwrites it):
  // 864 slots x 32KB = 28.3MB <= 33.5MB.  ML overlays dead Wq|Wk|Wv bf16.
  bf16_t* PO = (bf16_t*)d_out;
  float*  ML = (float*)Wcat;

  const int WN4 = D_MODEL * D_MODEL / 4;
  const int XN4 = MTOT * D_MODEL / 4;
  cast_kernel<<<XN4 / 256, 256, 0, stream>>>(x, xb, XN4);
  cast4_kernel<<<dim3(WN4 / 256, 4), 256, 0, stream>>>(Wq, Wk, Wv, Wo, Wcat, WN4);

  gemm_fused<<<dim3(MTOT / 128, 6144 / 128), 256, 0, stream>>>(
      xb, Wcat, 0, bq, bk, bv, Qb, Kb, Vtb, nullptr);

  flash_attn<<<dim3(768), 256, 0, stream>>>(Qb, Kb, Vtb, Ob, PO, ML);
  merge_kernel<<<dim3(352), 256, 0, stream>>>(PO, ML, Ob);

  gemm_fused<<<dim3(MTOT / 128, D_MODEL / 128), 256, 0, stream>>>(
      Ob, Wob, 1, bo, nullptr, nullptr, nullptr, nullptr, nullptr, out);
}